// Round 6
// baseline (174.866 us; speedup 1.0000x reference)
//
#include <hip/hip_runtime.h>
#include <hip/hip_bf16.h>

typedef __attribute__((ext_vector_type(4))) float  float4v;
typedef __attribute__((ext_vector_type(4))) short  short4v;
typedef __attribute__((ext_vector_type(8))) short  short8v;
typedef __attribute__((ext_vector_type(8))) __bf16 bf16x8;

constexpr int E_NUM = 64;
constexpr int HID   = 64;    // expert hidden
constexpr int DIN   = 1024;
constexpr int DOUT  = 1024;
constexpr int TPE   = 1024;  // tokens per expert = 65536/64

__device__ __forceinline__ short4v cvt4(float4v v) {
  short4v r;
#pragma unroll
  for (int j = 0; j < 4; j++) {
    __bf16 b = (__bf16)v[j];
    r[j] = __builtin_bit_cast(short, b);
  }
  return r;
}
__device__ __forceinline__ ushort cvt1(float f) {
  __bf16 b = (__bf16)f;
  return __builtin_bit_cast(ushort, b);
}

// ---------------------------------------------------------------------------
// Kernel 1: h[t, 0:64] = relu( x[t, :] @ W1[e]^T ), h stored bf16 in ws.
// Barrier-free streaming: W1[e] staged ONCE to LDS (128KB bf16, swizzled);
// each wave owns 16 token-rows and streams K=1024 in 32-k chunks, loading
// A-fragments DIRECTLY global->reg (depth-4 prefetch, no LDS, no barriers).
// grid = 64 experts * 8 = 512 blocks x 512 threads (1 block/CU, 2 rounds).
// ---------------------------------------------------------------------------
__global__ __launch_bounds__(512, 2) void fc1_stream_kernel(
    const float* __restrict__ x, const float* __restrict__ w1,
    ushort* __restrict__ hbuf) {
  __shared__ ushort Wl[HID * DIN];   // 64x1024 bf16 = 128KB, XOR-swizzled

  // XCD-bijective swizzle: nwg=512 (div 8) -> expert's 8 blocks on one XCD
  int nwg = (int)gridDim.x;
  int blk = (int)(blockIdx.x & 7) * (nwg >> 3) + (int)(blockIdx.x >> 3);
  int e  = blk >> 3;
  int rb = blk & 7;   // 128-token row-block within expert

  int tid  = (int)threadIdx.x;
  int lane = tid & 63;
  int wv   = tid >> 6;

  // ---- stage W1[e] -> LDS bf16 (16384 float4 chunks / 512 threads) ----
  const float* we = w1 + (size_t)e * HID * DIN;
#pragma unroll 8
  for (int i = 0; i < 32; i++) {
    int f = tid + i * 512;
    int row = f >> 8;        // 256 float4 per row
    int c4  = f & 255;
    float4v v = *(const float4v*)(we + (size_t)row * DIN + c4 * 4);
    *(short4v*)&Wl[(row * DIN + c4 * 4) ^ ((row & 7) << 3)] = cvt4(v);
  }
  __syncthreads();

  // ---- per-wave streaming GEMM: 16 rows x 64 cols, K=1024 ----
  int m16 = lane & 15;
  int kg  = (lane >> 4) * 8;                 // k sub-offset within fragment
  size_t tok0 = (size_t)e * TPE + rb * 128 + wv * 16 + m16;
  const float* xr = x + tok0 * DIN + kg;     // chunk c adds c*32 floats

  int rowk[4], xorv[4];
#pragma unroll
  for (int nf = 0; nf < 4; nf++) {
    int br = nf * 16 + m16;
    rowk[nf] = br * DIN + kg;
    xorv[nf] = (br & 7) << 3;
  }

  float4v acc[4];
#pragma unroll
  for (int nf = 0; nf < 4; nf++)
#pragma unroll
    for (int j = 0; j < 4; j++) acc[nf][j] = 0.f;

  auto LD = [&](int c, float4v& lo, float4v& hi) {
    lo = *(const float4v*)(xr + c * 32);
    hi = *(const float4v*)(xr + c * 32 + 4);
  };
  auto CHUNK = [&](float4v lo, float4v hi, int c) {
    short4v alo = cvt4(lo), ahi = cvt4(hi);
    short8v a;
#pragma unroll
    for (int j = 0; j < 4; j++) { a[j] = alo[j]; a[j + 4] = ahi[j]; }
    int k0 = c * 32;
#pragma unroll
    for (int nf = 0; nf < 4; nf++) {
      int idx = (rowk[nf] + k0) ^ xorv[nf];
      short8v b = *(const short8v*)&Wl[idx];
      acc[nf] = __builtin_amdgcn_mfma_f32_16x16x32_bf16(
          __builtin_bit_cast(bf16x8, a), __builtin_bit_cast(bf16x8, b),
          acc[nf], 0, 0, 0);
    }
  };

  // depth-4 prefetch pipeline over 32 chunks (static reg sets)
  float4v l0, h0, l1, h1, l2, h2, l3, h3;
  LD(0, l0, h0); LD(1, l1, h1); LD(2, l2, h2); LD(3, l3, h3);
  for (int i = 0; i < 7; i++) {
    int c = i * 4;
    CHUNK(l0, h0, c + 0); LD(c + 4, l0, h0);
    CHUNK(l1, h1, c + 1); LD(c + 5, l1, h1);
    CHUNK(l2, h2, c + 2); LD(c + 6, l2, h2);
    CHUNK(l3, h3, c + 3); LD(c + 7, l3, h3);
  }
  CHUNK(l0, h0, 28); CHUNK(l1, h1, 29);
  CHUNK(l2, h2, 30); CHUNK(l3, h3, 31);

  // ---- epilogue: relu -> LDS (reuse Wl) -> coalesced 16B stores ----
  __syncthreads();          // all waves done reading Wl
  ushort* hs = &Wl[0];      // 128x64 bf16 = 16KB
#pragma unroll
  for (int nf = 0; nf < 4; nf++) {
    int col = nf * 16 + m16;
#pragma unroll
    for (int j = 0; j < 4; j++) {
      int row = wv * 16 + ((lane >> 4) << 2) + j;
      hs[row * HID + col] = cvt1(fmaxf(acc[nf][j], 0.f));
    }
  }
  __syncthreads();
  size_t rowbase = (size_t)e * TPE + rb * 128;
#pragma unroll
  for (int i = 0; i < 2; i++) {
    int f = tid + i * 512;                 // 1024 chunks of 16B
    int row = f >> 3, c8 = (f & 7) * 8;
    short8v v = *(const short8v*)&hs[row * HID + c8];
    *(short8v*)(hbuf + (rowbase + row) * HID + c8) = v;
  }
}

// ---------------------------------------------------------------------------
// Kernel 2: y[t, o] = h[t, :] @ W2[e]^T. Single K=64 pass. (unchanged)
// Tile: BM=128 tokens x BN=128 outputs. 4 waves; wave owns 32 rows x 128 cols.
// grid = 64 experts * 8 * 8 = 4096.
// ---------------------------------------------------------------------------
__global__ __launch_bounds__(256) void fc2_kernel(
    const ushort* __restrict__ hbuf, const float* __restrict__ w2,
    float* __restrict__ y) {
  constexpr int BM = 128, BN = 128, K = 64;
  __shared__ ushort Hs[BM * K];
  __shared__ ushort Ws[BN * K];

  int nwg = (int)gridDim.x;  // 4096, divisible by 8
  int blk = (int)(blockIdx.x & 7) * (nwg >> 3) + (int)(blockIdx.x >> 3);

  int e  = blk >> 6;
  int mb = (blk >> 3) & 7;
  int nb = blk & 7;
  const ushort* he = hbuf + (size_t)(e * TPE + mb * BM) * K;
  const float*  we = w2 + ((size_t)e * DOUT + nb * BN) * K;

  int tid  = (int)threadIdx.x;
  int lane = tid & 63;
  int wv   = tid >> 6;

  // stage H: 128x64 bf16 (1024 chunks of 16B, fully contiguous region)
#pragma unroll
  for (int i = 0; i < 4; i++) {
    int f = tid + i * 256;
    int row = f >> 3, c8 = f & 7;
    short8v v = *(const short8v*)(he + (size_t)row * K + c8 * 8);
    *(short8v*)&Hs[(row * K + c8 * 8) ^ ((row & 7) << 3)] = v;
  }
  // stage W2: 128x64 fp32 -> bf16 (2048 float4 chunks, contiguous region)
#pragma unroll
  for (int i = 0; i < 8; i++) {
    int f = tid + i * 256;
    int row = f >> 4, c4 = f & 15;
    float4v v = *(const float4v*)(we + (size_t)row * K + c4 * 4);
    *(short4v*)&Ws[(row * K + c4 * 4) ^ ((row & 7) << 3)] = cvt4(v);
  }
  __syncthreads();

  float4v acc[2][8];
#pragma unroll
  for (int mf = 0; mf < 2; mf++)
#pragma unroll
    for (int nf = 0; nf < 8; nf++)
#pragma unroll
      for (int j = 0; j < 4; j++) acc[mf][nf][j] = 0.f;

  int kg = (lane >> 4) * 8;
#pragma unroll
  for (int kk = 0; kk < K; kk += 32) {
    int k0 = kk + kg;
    short8v a[2];
#pragma unroll
    for (int mf = 0; mf < 2; mf++) {
      int arr = wv * 32 + mf * 16 + (lane & 15);
      a[mf] = *(const short8v*)&Hs[(arr * K + k0) ^ ((arr & 7) << 3)];
    }
#pragma unroll
    for (int nf = 0; nf < 8; nf++) {
      int br = nf * 16 + (lane & 15);
      short8v b = *(const short8v*)&Ws[(br * K + k0) ^ ((br & 7) << 3)];
#pragma unroll
      for (int mf = 0; mf < 2; mf++)
        acc[mf][nf] = __builtin_amdgcn_mfma_f32_16x16x32_bf16(
            __builtin_bit_cast(bf16x8, a[mf]), __builtin_bit_cast(bf16x8, b),
            acc[mf][nf], 0, 0, 0);
    }
  }

  // epilogue: direct fp32 stores (per row, nf-unrolled -> 512B dense per row)
  size_t row0 = (size_t)(e * TPE + mb * BM) + wv * 32 + ((lane >> 4) << 2);
  int col0 = nb * BN + (lane & 15);
#pragma unroll
  for (int mf = 0; mf < 2; mf++) {
#pragma unroll
    for (int j = 0; j < 4; j++) {
      float* yr = y + (row0 + mf * 16 + j) * DOUT + col0;
#pragma unroll
      for (int nf = 0; nf < 8; nf++) yr[nf * 16] = acc[mf][nf][j];
    }
  }
}

extern "C" void kernel_launch(void* const* d_in, const int* in_sizes, int n_in,
                              void* d_out, int out_size, void* d_ws, size_t ws_size,
                              hipStream_t stream) {
  const float* x  = (const float*)d_in[0];
  // d_in[1] = fwd_expert_count: equal groups (T/E) by problem construction
  const float* w1 = (const float*)d_in[2];
  const float* w2 = (const float*)d_in[3];
  float* yout = (float*)d_out;
  ushort* hbuf = (ushort*)d_ws;   // T * 64 bf16 = 8.4 MB scratch

  fc1_stream_kernel<<<E_NUM * 8, 512, 0, stream>>>(x, w1, hbuf);
  fc2_kernel<<<E_NUM * 64, 256, 0, stream>>>(hbuf, w2, yout);
}

// Round 7
// 155.932 us; speedup vs baseline: 1.1214x; 1.1214x over previous
//
#include <hip/hip_runtime.h>
#include <hip/hip_bf16.h>

typedef __attribute__((ext_vector_type(4))) float  float4v;
typedef __attribute__((ext_vector_type(4))) short  short4v;
typedef __attribute__((ext_vector_type(8))) short  short8v;
typedef __attribute__((ext_vector_type(8))) __bf16 bf16x8;

constexpr int E_NUM = 64;
constexpr int HID   = 64;    // expert hidden
constexpr int DIN   = 1024;
constexpr int DOUT  = 1024;
constexpr int TPE   = 1024;  // tokens per expert = 65536/64

__device__ __forceinline__ short4v cvt4(float4v v) {
  short4v r;
#pragma unroll
  for (int j = 0; j < 4; j++) {
    __bf16 b = (__bf16)v[j];
    r[j] = __builtin_bit_cast(short, b);
  }
  return r;
}
__device__ __forceinline__ ushort cvt1(float f) {
  __bf16 b = (__bf16)f;
  return __builtin_bit_cast(ushort, b);
}

// ---------------------------------------------------------------------------
// Kernel 1: h[t,0:64] = relu(x[t,:] @ W1[e]^T), h bf16 in ws.
// BM=64, BK=128. X staged fp32 via global_load_lds dwordx4 (dbuf 2x32KB,
// linear LDS dest + XOR-swizzled GLOBAL source; cvt->bf16 at fragment read).
// W1 tile bf16 single-buffer (16KB, reg-staged, 2 barriers/step).
// LDS total 80KB -> 2 blocks/CU (16 waves). grid = 64*16 = 1024.
// ---------------------------------------------------------------------------
__global__ __launch_bounds__(512, 4) void fc1_kernel(
    const float* __restrict__ x, const float* __restrict__ w1,
    ushort* __restrict__ hbuf) {
  constexpr int BM = 64, BK = 128;
  __shared__ float  Xs[2][BM * BK];   // 2 x 32KB fp32
  __shared__ ushort Wb[HID * BK];     // 16KB bf16, XOR-swizzled

  // XCD-bijective swizzle: nwg=1024 (div 8)
  int nwg = (int)gridDim.x;
  int blk = (int)(blockIdx.x & 7) * (nwg >> 3) + (int)(blockIdx.x >> 3);
  int e  = blk >> 4;
  int rb = blk & 15;
  const float* xe = x  + (size_t)(e * TPE + rb * BM) * DIN;
  const float* we = w1 + (size_t)e * HID * DIN;

  int tid  = (int)threadIdx.x;
  int lane = tid & 63;
  int wv   = tid >> 6;

  // --- X staging: 32 gload_lds insts/step, 4 per wave; inst i = row-pair
  // rp = wv*4+i (1KB). lane l -> row 2rp+(l>>5), src chunk (l&31)^(row&7).
  int xgoff[4];
#pragma unroll
  for (int i = 0; i < 4; i++) {
    int rp = wv * 4 + i;
    int r  = rp * 2 + (lane >> 5);
    int ch = (lane & 31) ^ (r & 7);       // source swizzle (within 128B line)
    xgoff[i] = r * DIN + ch * 4;
  }
  auto GLOADX = [&](int kt, int b) {
#pragma unroll
    for (int i = 0; i < 4; i++) {
      int rp = wv * 4 + i;
      __builtin_amdgcn_global_load_lds(
          (__attribute__((address_space(1))) void*)(xe + xgoff[i] + kt),
          (__attribute__((address_space(3))) void*)(&Xs[b][rp * 2 * BK]),
          16, 0, 0);
    }
  };

  // --- W staging (reg path): thread t -> row t>>3, chunks (t&7)*2 + {0,1} ---
  int wrow = tid >> 3;
  int wc   = (tid & 7) * 2;
  float4v wreg[4];
  auto WLOAD = [&](int kt) {
    const float* p = we + (size_t)wrow * DIN + kt + wc * 8;
    wreg[0] = *(const float4v*)(p);
    wreg[1] = *(const float4v*)(p + 4);
    wreg[2] = *(const float4v*)(p + 8);
    wreg[3] = *(const float4v*)(p + 12);
  };
  auto WWRITE = [&]() {
#pragma unroll
    for (int j = 0; j < 2; j++) {
      short4v a = cvt4(wreg[j * 2]), b = cvt4(wreg[j * 2 + 1]);
      short8v s;
#pragma unroll
      for (int q = 0; q < 4; q++) { s[q] = a[q]; s[q + 4] = b[q]; }
      int c = (wc + j) ^ (wrow & 7);      // write-side swizzle
      *(short8v*)&Wb[wrow * BK + c * 8] = s;
    }
  };

  // wave -> output sub-tile: 4 mf-groups x 2 col-halves
  int m16 = lane & 15;
  int kg  = (lane >> 4) * 8;
  int mf  = wv >> 1;
  int nb2 = (wv & 1) * 2;
  int ar  = mf * 16 + m16;

  float4v acc[2];
#pragma unroll
  for (int j = 0; j < 2; j++)
#pragma unroll
    for (int q = 0; q < 4; q++) acc[j][q] = 0.f;

  auto MMA = [&](int b) {
    const float* xb = &Xs[b][ar * BK];
#pragma unroll
    for (int kk = 0; kk < BK; kk += 32) {
      int k0 = kk + kg;
      int c0 = k0 >> 2;                    // even
      float4v x0 = *(const float4v*)(xb + (((c0    ) ^ (ar & 7)) << 2));
      float4v x1 = *(const float4v*)(xb + (((c0 + 1) ^ (ar & 7)) << 2));
      short4v a0 = cvt4(x0), a1 = cvt4(x1);
      short8v a;
#pragma unroll
      for (int q = 0; q < 4; q++) { a[q] = a0[q]; a[q + 4] = a1[q]; }
#pragma unroll
      for (int j = 0; j < 2; j++) {
        int br = (nb2 + j) * 16 + m16;
        short8v bf = *(const short8v*)&Wb[br * BK + (((k0 >> 3) ^ (br & 7)) << 3)];
        acc[j] = __builtin_amdgcn_mfma_f32_16x16x32_bf16(
            __builtin_bit_cast(bf16x8, a), __builtin_bit_cast(bf16x8, bf),
            acc[j], 0, 0, 0);
      }
    }
  };

  // ---- prologue ----
  GLOADX(0, 0);
  WLOAD(0);
  WWRITE();          // waits its vmcnt, ds_writes Wb
  __syncthreads();   // drains vmcnt/lgkm: X(0) in LDS, Wb visible

  // ---- K loop: 8 steps, 2 barriers/step ----
#pragma unroll
  for (int s = 0; s < 8; s++) {
    int b = s & 1;
    if (s < 7) {
      GLOADX((s + 1) * BK, b ^ 1);   // in flight under MMA
      WLOAD((s + 1) * BK);
    }
    MMA(b);
    __syncthreads();   // all Wb/Xs[b] reads done; drains X(s+1)/W loads
    if (s < 7) WWRITE();
    __syncthreads();   // Wb(s+1) ready
  }

  // ---- epilogue: relu -> LDS (linear, reuse Xs[0]) -> 16B stores ----
  ushort* hs = (ushort*)&Xs[0][0];   // 64x64 bf16 = 8KB
#pragma unroll
  for (int j = 0; j < 2; j++) {
    int col = (nb2 + j) * 16 + m16;
#pragma unroll
    for (int q = 0; q < 4; q++) {
      int row = mf * 16 + ((lane >> 4) << 2) + q;
      hs[row * HID + col] = cvt1(fmaxf(acc[j][q], 0.f));
    }
  }
  __syncthreads();
  size_t rowbase = (size_t)e * TPE + rb * BM;
  int row = tid >> 3, c8 = (tid & 7) * 8;   // 512 x 16B = 8KB
  short8v v = *(const short8v*)&hs[row * HID + c8];
  *(short8v*)(hbuf + (rowbase + row) * HID + c8) = v;
}

// ---------------------------------------------------------------------------
// Kernel 2: y[t, o] = h[t, :] @ W2[e]^T. Single K=64 pass. (unchanged)
// Tile: BM=128 tokens x BN=128 outputs. 4 waves; wave owns 32 rows x 128 cols.
// grid = 64 experts * 8 * 8 = 4096.
// ---------------------------------------------------------------------------
__global__ __launch_bounds__(256) void fc2_kernel(
    const ushort* __restrict__ hbuf, const float* __restrict__ w2,
    float* __restrict__ y) {
  constexpr int BM = 128, BN = 128, K = 64;
  __shared__ ushort Hs[BM * K];
  __shared__ ushort Ws[BN * K];

  int nwg = (int)gridDim.x;  // 4096, divisible by 8
  int blk = (int)(blockIdx.x & 7) * (nwg >> 3) + (int)(blockIdx.x >> 3);

  int e  = blk >> 6;
  int mb = (blk >> 3) & 7;
  int nb = blk & 7;
  const ushort* he = hbuf + (size_t)(e * TPE + mb * BM) * K;
  const float*  we = w2 + ((size_t)e * DOUT + nb * BN) * K;

  int tid  = (int)threadIdx.x;
  int lane = tid & 63;
  int wv   = tid >> 6;

  // stage H: 128x64 bf16 (1024 chunks of 16B, fully contiguous region)
#pragma unroll
  for (int i = 0; i < 4; i++) {
    int f = tid + i * 256;
    int row = f >> 3, c8 = f & 7;
    short8v v = *(const short8v*)(he + (size_t)row * K + c8 * 8);
    *(short8v*)&Hs[(row * K + c8 * 8) ^ ((row & 7) << 3)] = v;
  }
  // stage W2: 128x64 fp32 -> bf16 (2048 float4 chunks, contiguous region)
#pragma unroll
  for (int i = 0; i < 8; i++) {
    int f = tid + i * 256;
    int row = f >> 4, c4 = f & 15;
    float4v v = *(const float4v*)(we + (size_t)row * K + c4 * 4);
    *(short4v*)&Ws[(row * K + c4 * 4) ^ ((row & 7) << 3)] = cvt4(v);
  }
  __syncthreads();

  float4v acc[2][8];
#pragma unroll
  for (int mf = 0; mf < 2; mf++)
#pragma unroll
    for (int nf = 0; nf < 8; nf++)
#pragma unroll
      for (int j = 0; j < 4; j++) acc[mf][nf][j] = 0.f;

  int kg = (lane >> 4) * 8;
#pragma unroll
  for (int kk = 0; kk < K; kk += 32) {
    int k0 = kk + kg;
    short8v a[2];
#pragma unroll
    for (int mf = 0; mf < 2; mf++) {
      int arr = wv * 32 + mf * 16 + (lane & 15);
      a[mf] = *(const short8v*)&Hs[(arr * K + k0) ^ ((arr & 7) << 3)];
    }
#pragma unroll
    for (int nf = 0; nf < 8; nf++) {
      int br = nf * 16 + (lane & 15);
      short8v b = *(const short8v*)&Ws[(br * K + k0) ^ ((br & 7) << 3)];
#pragma unroll
      for (int mf = 0; mf < 2; mf++)
        acc[mf][nf] = __builtin_amdgcn_mfma_f32_16x16x32_bf16(
            __builtin_bit_cast(bf16x8, a[mf]), __builtin_bit_cast(bf16x8, b),
            acc[mf][nf], 0, 0, 0);
    }
  }

  // epilogue: direct fp32 stores (per row, nf-unrolled -> 512B dense per row)
  size_t row0 = (size_t)(e * TPE + mb * BM) + wv * 32 + ((lane >> 4) << 2);
  int col0 = nb * BN + (lane & 15);
#pragma unroll
  for (int mf = 0; mf < 2; mf++) {
#pragma unroll
    for (int j = 0; j < 4; j++) {
      float* yr = y + (row0 + mf * 16 + j) * DOUT + col0;
#pragma unroll
      for (int nf = 0; nf < 8; nf++) yr[nf * 16] = acc[mf][nf][j];
    }
  }
}

extern "C" void kernel_launch(void* const* d_in, const int* in_sizes, int n_in,
                              void* d_out, int out_size, void* d_ws, size_t ws_size,
                              hipStream_t stream) {
  const float* x  = (const float*)d_in[0];
  // d_in[1] = fwd_expert_count: equal groups (T/E) by problem construction
  const float* w1 = (const float*)d_in[2];
  const float* w2 = (const float*)d_in[3];
  float* yout = (float*)d_out;
  ushort* hbuf = (ushort*)d_ws;   // T * 64 bf16 = 8.4 MB scratch

  fc1_kernel<<<E_NUM * 16, 512, 0, stream>>>(x, w1, hbuf);
  fc2_kernel<<<E_NUM * 64, 256, 0, stream>>>(hbuf, w2, yout);
}